// Round 7
// baseline (6205.614 us; speedup 1.0000x reference)
//
#include <hip/hip_runtime.h>
#include <hip/hip_bf16.h>

#define T_STEPS 512
#define BATCH   64
#define IDIM    512
#define HDIM    1024
#define ODIM    512
#define NWG     128
#define TPB     512           // 8 waves: split-K 8 ways
#define TPB2    256
#define JS      8             // hidden units per WG -> 32 gate cols

typedef __bf16 bf16_t;
typedef bf16_t bf16x8 __attribute__((ext_vector_type(8)));
typedef float  f32x4  __attribute__((ext_vector_type(4)));
typedef unsigned short u16;
typedef unsigned int   u32;
typedef u16 u16x8 __attribute__((ext_vector_type(8)));

// ws layout (u32): [0,65536) h double buffer; [65536,66560) counters @128B; then X_bf16
#define HBUF_U32 65536
#define CNT_U32  1024
#define XB_U16_OFF (2 * (HBUF_U32 + CNT_U32))

__device__ __forceinline__ float sigmoidf_fast(float x) {
  return 1.0f / (1.0f + __expf(-x));
}
__device__ __forceinline__ float tanhf_fast(float x) {
  float ax = fabsf(x);
  float e  = __expf(-2.0f * ax);
  return copysignf((1.0f - e) / (1.0f + e), x);
}

__global__ void k_init(u32* w) {
  int i = blockIdx.x * blockDim.x + threadIdx.x;
  for (int idx = i; idx < HBUF_U32 + CNT_U32; idx += gridDim.x * blockDim.x) w[idx] = 0u;
}

__global__ __launch_bounds__(TPB2) void k_xcvt(const float* __restrict__ X,
                                               u16* __restrict__ Xb) {
  size_t i = ((size_t)blockIdx.x * TPB2 + threadIdx.x) * 8;
  f32x4 a = *(const f32x4*)(X + i);
  f32x4 b = *(const f32x4*)(X + i + 4);
  u16x8 o;
  o[0] = __builtin_bit_cast(u16, (bf16_t)a[0]);
  o[1] = __builtin_bit_cast(u16, (bf16_t)a[1]);
  o[2] = __builtin_bit_cast(u16, (bf16_t)a[2]);
  o[3] = __builtin_bit_cast(u16, (bf16_t)a[3]);
  o[4] = __builtin_bit_cast(u16, (bf16_t)b[0]);
  o[5] = __builtin_bit_cast(u16, (bf16_t)b[1]);
  o[6] = __builtin_bit_cast(u16, (bf16_t)b[2]);
  o[7] = __builtin_bit_cast(u16, (bf16_t)b[3]);
  *(u16x8*)(Xb + i) = o;
}

__device__ __forceinline__ bf16x8 cvt8(const float* src) {
  f32x4 u = *(const f32x4*)src;
  f32x4 v = *(const f32x4*)(src + 4);
  bf16x8 t;
  t[0] = (bf16_t)u[0]; t[1] = (bf16_t)u[1]; t[2] = (bf16_t)u[2]; t[3] = (bf16_t)u[3];
  t[4] = (bf16_t)v[0]; t[5] = (bf16_t)v[1]; t[6] = (bf16_t)v[2]; t[7] = (bf16_t)v[3];
  return t;
}

#define MFA(CT, BT, AF, WI) \
  acc[CT][BT] = __builtin_amdgcn_mfma_f32_16x16x32_bf16((AF), wf[(WI)*2+(CT)], acc[CT][BT], 0, 0, 0)

// pinned h load, NORMAL caching (L2-filtered broadcast); freshness via post-poll acquire fence
#define GLD(DST, PTR, OFFB) \
  asm volatile("global_load_dwordx4 %0, %1, off offset:" OFFB : "=v"(DST) : "v"(PTR))

#define GWS 76   // gw inner stride (floats): 16B-aligned, 2-way banks both sides (conflicts=0)

__global__ __launch_bounds__(TPB, 2) void k_lstm(
    const u16* __restrict__ Xb, const float* __restrict__ Wih,
    const float* __restrict__ Whh, const float* __restrict__ bih,
    const float* __restrict__ bhh, u16* __restrict__ hbuf,
    u32* __restrict__ cnt) {
  __shared__ float gw[8][32][GWS];   // 77.8 KB cross-wave partial sums

  const int wg   = blockIdx.x;
  const int tid  = threadIdx.x;
  const int w    = tid >> 6;        // wave = k-split slice
  const int lane = tid & 63;
  const int am   = lane & 15;
  const int kg   = lane >> 4;

  // ---- time-invariant weights in registers: wave w owns k-tiles w+8i, i=0..5 ----
  bf16x8 wf[12];
  {
    const int j8 = am & 7, gsel = am >> 3;
    #pragma unroll
    for (int ct = 0; ct < 2; ++ct) {
      int gr = (ct * 2 + gsel) * HDIM + wg * JS + j8;
      #pragma unroll
      for (int i = 0; i < 2; ++i)
        wf[i * 2 + ct] = cvt8(Wih + (size_t)gr * IDIM + (w + 8 * i) * 32 + kg * 8);
      #pragma unroll
      for (int i = 2; i < 6; ++i)
        wf[i * 2 + ct] = cvt8(Whh + (size_t)gr * HDIM + (w + 8 * i) * 32 + kg * 8 - IDIM);
    }
  }

  const int eb = tid >> 3;
  const int ej = tid & 7;
  float bias[4];
  #pragma unroll
  for (int g = 0; g < 4; ++g) {
    int r = g * HDIM + wg * JS + ej;
    bias[g] = bih[r] + bhh[r];
  }
  float c = 0.f;

  f32x4 acc[2][4];

  // X-part phase: acc += X(tt) @ Wih-slice
  auto xphase = [&](int tt) {
    const u16* xb = Xb + ((size_t)tt * BATCH + am) * IDIM + w * 32 + kg * 8;
    #pragma unroll
    for (int ti = 0; ti < 2; ++ti)
      #pragma unroll
      for (int bt = 0; bt < 4; ++bt) {
        bf16x8 xa = *(const bf16x8*)(xb + (size_t)bt * 16 * IDIM + ti * 256);
        MFA(0, bt, xa, ti);
        MFA(1, bt, xa, ti);
      }
  };

  // prologue: X(0) partials
  #pragma unroll
  for (int ct = 0; ct < 2; ++ct)
    #pragma unroll
    for (int bt = 0; bt < 4; ++bt)
      acc[ct][bt] = (f32x4){0.f, 0.f, 0.f, 0.f};
  xphase(0);

  int cur = 0;
  for (int t = 0; t < T_STEPS; ++t) {
    // ---- 16 pinned h loads (L2-cached; fence already executed), counted waits ----
    bf16x8 hA[8], hB[8];
    const u16* hb0 = hbuf + (size_t)cur * BATCH * HDIM + (size_t)am * HDIM + w * 32 + kg * 8;
    const u16* hb1 = hb0 + 16 * HDIM;
    const u16* hb2 = hb0 + 32 * HDIM;
    const u16* hb3 = hb0 + 48 * HDIM;
    GLD(hA[0], hb0, "0");    GLD(hA[1], hb1, "0");    GLD(hA[2], hb2, "0");    GLD(hA[3], hb3, "0");
    GLD(hA[4], hb0, "512");  GLD(hA[5], hb1, "512");  GLD(hA[6], hb2, "512");  GLD(hA[7], hb3, "512");
    GLD(hB[0], hb0, "1024"); GLD(hB[1], hb1, "1024"); GLD(hB[2], hb2, "1024"); GLD(hB[3], hb3, "1024");
    GLD(hB[4], hb0, "1536"); GLD(hB[5], hb1, "1536"); GLD(hB[6], hb2, "1536"); GLD(hB[7], hb3, "1536");
    __builtin_amdgcn_sched_barrier(0);

    asm volatile("s_waitcnt vmcnt(8)" ::: "memory");   // hA landed
    __builtin_amdgcn_sched_barrier(0);
    #pragma unroll
    for (int q = 0; q < 2; ++q)
      #pragma unroll
      for (int bt = 0; bt < 4; ++bt) {
        MFA(0, bt, hA[q * 4 + bt], 2 + q);
        MFA(1, bt, hA[q * 4 + bt], 2 + q);
      }

    asm volatile("s_waitcnt vmcnt(0)" ::: "memory");   // hB landed
    __builtin_amdgcn_sched_barrier(0);
    #pragma unroll
    for (int q = 0; q < 2; ++q)
      #pragma unroll
      for (int bt = 0; bt < 4; ++bt) {
        MFA(0, bt, hB[q * 4 + bt], 4 + q);
        MFA(1, bt, hB[q * 4 + bt], 4 + q);
      }

    // partial sums -> LDS
    #pragma unroll
    for (int ct = 0; ct < 2; ++ct)
      #pragma unroll
      for (int bt = 0; bt < 4; ++bt)
        *(f32x4*)&gw[w][ct * 16 + am][bt * 16 + kg * 4] = acc[ct][bt];
    __syncthreads();   // #1: partials visible

    // reduce over 8 waves + activations; one cell per thread
    {
      float s0 = 0.f, s1 = 0.f, s2 = 0.f, s3 = 0.f;
      #pragma unroll
      for (int ww = 0; ww < 8; ++ww) {
        s0 += gw[ww][ej][eb];
        s1 += gw[ww][8 + ej][eb];
        s2 += gw[ww][16 + ej][eb];
        s3 += gw[ww][24 + ej][eb];
      }
      float pi = s0 + bias[0], pf = s1 + bias[1];
      float pg = s2 + bias[2], po = s3 + bias[3];
      c = sigmoidf_fast(pf) * c + sigmoidf_fast(pi) * tanhf_fast(pg);
      float h = sigmoidf_fast(po) * tanhf_fast(c);
      u16 hu = __builtin_bit_cast(u16, (bf16_t)h);
      u16* hp = hbuf + (size_t)(cur ^ 1) * BATCH * HDIM + (size_t)eb * HDIM + wg * JS + ej;
      asm volatile("global_store_short %0, %1, off sc0 sc1"   // write-through to LLC
                   :: "v"(hp), "v"((u32)hu) : "memory");
    }
    __syncthreads();   // #2: includes vmcnt(0) -> all 8 waves' h stores at LLC

    if (t != T_STEPS - 1) {
      if (tid == 0) atomicAdd(&cnt[(wg & 15) * 32], 1u);   // arrive (16 spread lines)

      // overlap the barrier wait with next step's X-part MFMAs (pre-fence; consumed to regs)
      #pragma unroll
      for (int ct = 0; ct < 2; ++ct)
        #pragma unroll
        for (int bt = 0; bt < 4; ++bt)
          acc[ct][bt] = (f32x4){0.f, 0.f, 0.f, 0.f};
      xphase(t + 1);

      // every wave polls independently (no release syncthreads)
      {
        u32 target = (u32)(t + 1) * (u32)NWG;
        while (true) {
          u32 v = (lane < 16)
            ? __hip_atomic_load(&cnt[lane * 32], __ATOMIC_RELAXED, __HIP_MEMORY_SCOPE_AGENT)
            : 0u;
          v += __shfl_xor(v, 1);
          v += __shfl_xor(v, 2);
          v += __shfl_xor(v, 4);
          v += __shfl_xor(v, 8);
          if (__shfl(v, 0) >= target) break;
          __builtin_amdgcn_s_sleep(1);
        }
        __builtin_amdgcn_fence(__ATOMIC_ACQUIRE, "agent");  // buffer_inv: h(t+1) refetch via L2
        __builtin_amdgcn_sched_barrier(0);
      }
    }
    cur ^= 1;
  }
}

__global__ __launch_bounds__(TPB2) void k_out(
    const u16* __restrict__ hfin, const float* __restrict__ Who,
    const float* __restrict__ bho, float* __restrict__ out) {
  int gid = blockIdx.x * TPB2 + threadIdx.x;  // 0..32767
  int b   = gid & 63;
  int oc  = gid >> 6;
  const u16* hrow = hfin + b * HDIM;
  const float* wrow = Who + oc * HDIM;
  float s = bho[oc];
  for (int k = 0; k < HDIM; k += 8) {
    bf16x8 hv = *(const bf16x8*)(hrow + k);
    f32x4 w0 = *(const f32x4*)(wrow + k);
    f32x4 w1 = *(const f32x4*)(wrow + k + 4);
    s += (float)hv[0] * w0[0] + (float)hv[1] * w0[1] + (float)hv[2] * w0[2] + (float)hv[3] * w0[3]
       + (float)hv[4] * w1[0] + (float)hv[5] * w1[1] + (float)hv[6] * w1[2] + (float)hv[7] * w1[3];
  }
  out[b * ODIM + oc] = s;
}

extern "C" void kernel_launch(void* const* d_in, const int* in_sizes, int n_in,
                              void* d_out, int out_size, void* d_ws, size_t ws_size,
                              hipStream_t stream) {
  const float* X   = (const float*)d_in[0];
  const float* Wih = (const float*)d_in[1];
  const float* Whh = (const float*)d_in[2];
  const float* bih = (const float*)d_in[3];
  const float* bhh = (const float*)d_in[4];
  const float* Who = (const float*)d_in[5];
  const float* bho = (const float*)d_in[6];

  u32* ws32 = (u32*)d_ws;
  u16* hbuf = (u16*)d_ws;
  u32* cnt  = ws32 + HBUF_U32;
  u16* Xb   = (u16*)d_ws + XB_U16_OFF;

  k_init<<<64, TPB2, 0, stream>>>(ws32);
  k_xcvt<<<(T_STEPS * BATCH * IDIM) / (TPB2 * 8), TPB2, 0, stream>>>(X, Xb);
  k_lstm<<<NWG, TPB, 0, stream>>>(Xb, Wih, Whh, bih, bhh, hbuf, cnt);
  k_out<<<(BATCH * ODIM) / TPB2, TPB2, 0, stream>>>(hbuf, Who, bho, (float*)d_out);
}

// Round 8
// 3744.903 us; speedup vs baseline: 1.6571x; 1.6571x over previous
//
#include <hip/hip_runtime.h>
#include <hip/hip_bf16.h>

#define T_STEPS 512
#define BATCH   64
#define IDIM    512
#define HDIM    1024
#define ODIM    512
#define NWG     128
#define TPB     512           // 8 waves: split-K 8 ways
#define TPB2    256
#define JS      8             // hidden units per WG -> 32 gate cols

typedef __bf16 bf16_t;
typedef bf16_t bf16x8 __attribute__((ext_vector_type(8)));
typedef float  f32x4  __attribute__((ext_vector_type(4)));
typedef unsigned short u16;
typedef unsigned int   u32;
typedef u16 u16x8 __attribute__((ext_vector_type(8)));

// ws layout (u32): [0,65536) h double buffer; [65536,66560) counters @128B; then X_bf16
#define HBUF_U32 65536
#define CNT_U32  1024
#define XB_U16_OFF (2 * (HBUF_U32 + CNT_U32))

__device__ __forceinline__ float sigmoidf_fast(float x) {
  return 1.0f / (1.0f + __expf(-x));
}
__device__ __forceinline__ float tanhf_fast(float x) {
  float ax = fabsf(x);
  float e  = __expf(-2.0f * ax);
  return copysignf((1.0f - e) / (1.0f + e), x);
}

__global__ void k_init(u32* w) {
  int i = blockIdx.x * blockDim.x + threadIdx.x;
  for (int idx = i; idx < HBUF_U32 + CNT_U32; idx += gridDim.x * blockDim.x) w[idx] = 0u;
}

__global__ __launch_bounds__(TPB2) void k_xcvt(const float* __restrict__ X,
                                               u16* __restrict__ Xb) {
  size_t i = ((size_t)blockIdx.x * TPB2 + threadIdx.x) * 8;
  f32x4 a = *(const f32x4*)(X + i);
  f32x4 b = *(const f32x4*)(X + i + 4);
  u16x8 o;
  o[0] = __builtin_bit_cast(u16, (bf16_t)a[0]);
  o[1] = __builtin_bit_cast(u16, (bf16_t)a[1]);
  o[2] = __builtin_bit_cast(u16, (bf16_t)a[2]);
  o[3] = __builtin_bit_cast(u16, (bf16_t)a[3]);
  o[4] = __builtin_bit_cast(u16, (bf16_t)b[0]);
  o[5] = __builtin_bit_cast(u16, (bf16_t)b[1]);
  o[6] = __builtin_bit_cast(u16, (bf16_t)b[2]);
  o[7] = __builtin_bit_cast(u16, (bf16_t)b[3]);
  *(u16x8*)(Xb + i) = o;
}

__device__ __forceinline__ bf16x8 cvt8(const float* src) {
  f32x4 u = *(const f32x4*)src;
  f32x4 v = *(const f32x4*)(src + 4);
  bf16x8 t;
  t[0] = (bf16_t)u[0]; t[1] = (bf16_t)u[1]; t[2] = (bf16_t)u[2]; t[3] = (bf16_t)u[3];
  t[4] = (bf16_t)v[0]; t[5] = (bf16_t)v[1]; t[6] = (bf16_t)v[2]; t[7] = (bf16_t)v[3];
  return t;
}

#define MFA(CT, BT, AF, WI) \
  acc[CT][BT] = __builtin_amdgcn_mfma_f32_16x16x32_bf16((AF), wf[(WI)*2+(CT)], acc[CT][BT], 0, 0, 0)

// pinned h load, L2-cached: producer's sc0 write-through store keeps peer L2s coherent
// (empirically validated r4/r5: cached h loads + no fence, bit-identical absmax)
#define GLD(DST, PTR, OFFB) \
  asm volatile("global_load_dwordx4 %0, %1, off offset:" OFFB : "=v"(DST) : "v"(PTR))

#define GWS 76   // gw inner stride (floats): 16B-aligned, 2-way banks both sides (conflicts=0)

__global__ __launch_bounds__(TPB, 2) void k_lstm(
    const u16* __restrict__ Xb, const float* __restrict__ Wih,
    const float* __restrict__ Whh, const float* __restrict__ bih,
    const float* __restrict__ bhh, u16* __restrict__ hbuf,
    u32* __restrict__ cnt) {
  __shared__ float gw[8][32][GWS];   // 77.8 KB cross-wave partial sums

  const int wg   = blockIdx.x;
  const int tid  = threadIdx.x;
  const int w    = tid >> 6;        // wave = k-split slice
  const int lane = tid & 63;
  const int am   = lane & 15;
  const int kg   = lane >> 4;

  // ---- time-invariant weights in registers: wave w owns k-tiles w+8i, i=0..5 ----
  bf16x8 wf[12];
  {
    const int j8 = am & 7, gsel = am >> 3;
    #pragma unroll
    for (int ct = 0; ct < 2; ++ct) {
      int gr = (ct * 2 + gsel) * HDIM + wg * JS + j8;
      #pragma unroll
      for (int i = 0; i < 2; ++i)
        wf[i * 2 + ct] = cvt8(Wih + (size_t)gr * IDIM + (w + 8 * i) * 32 + kg * 8);
      #pragma unroll
      for (int i = 2; i < 6; ++i)
        wf[i * 2 + ct] = cvt8(Whh + (size_t)gr * HDIM + (w + 8 * i) * 32 + kg * 8 - IDIM);
    }
  }

  const int eb = tid >> 3;
  const int ej = tid & 7;
  float bias[4];
  #pragma unroll
  for (int g = 0; g < 4; ++g) {
    int r = g * HDIM + wg * JS + ej;
    bias[g] = bih[r] + bhh[r];
  }
  float c = 0.f;

  f32x4 acc[2][4];

  // X-part phase: acc += X(tt) @ Wih-slice (L2-warm, never invalidated)
  auto xphase = [&](int tt) {
    const u16* xb = Xb + ((size_t)tt * BATCH + am) * IDIM + w * 32 + kg * 8;
    #pragma unroll
    for (int ti = 0; ti < 2; ++ti)
      #pragma unroll
      for (int bt = 0; bt < 4; ++bt) {
        bf16x8 xa = *(const bf16x8*)(xb + (size_t)bt * 16 * IDIM + ti * 256);
        MFA(0, bt, xa, ti);
        MFA(1, bt, xa, ti);
      }
  };

  // prologue: X(0) partials
  #pragma unroll
  for (int ct = 0; ct < 2; ++ct)
    #pragma unroll
    for (int bt = 0; bt < 4; ++bt)
      acc[ct][bt] = (f32x4){0.f, 0.f, 0.f, 0.f};
  xphase(0);

  int cur = 0;
  for (int t = 0; t < T_STEPS; ++t) {
    // ---- 16 pinned h loads (L2-cached; coherent via producer sc0 stores), counted waits ----
    bf16x8 hA[8], hB[8];
    const u16* hb0 = hbuf + (size_t)cur * BATCH * HDIM + (size_t)am * HDIM + w * 32 + kg * 8;
    const u16* hb1 = hb0 + 16 * HDIM;
    const u16* hb2 = hb0 + 32 * HDIM;
    const u16* hb3 = hb0 + 48 * HDIM;
    GLD(hA[0], hb0, "0");    GLD(hA[1], hb1, "0");    GLD(hA[2], hb2, "0");    GLD(hA[3], hb3, "0");
    GLD(hA[4], hb0, "512");  GLD(hA[5], hb1, "512");  GLD(hA[6], hb2, "512");  GLD(hA[7], hb3, "512");
    GLD(hB[0], hb0, "1024"); GLD(hB[1], hb1, "1024"); GLD(hB[2], hb2, "1024"); GLD(hB[3], hb3, "1024");
    GLD(hB[4], hb0, "1536"); GLD(hB[5], hb1, "1536"); GLD(hB[6], hb2, "1536"); GLD(hB[7], hb3, "1536");
    __builtin_amdgcn_sched_barrier(0);

    asm volatile("s_waitcnt vmcnt(8)" ::: "memory");   // hA landed
    __builtin_amdgcn_sched_barrier(0);
    #pragma unroll
    for (int q = 0; q < 2; ++q)
      #pragma unroll
      for (int bt = 0; bt < 4; ++bt) {
        MFA(0, bt, hA[q * 4 + bt], 2 + q);
        MFA(1, bt, hA[q * 4 + bt], 2 + q);
      }

    asm volatile("s_waitcnt vmcnt(0)" ::: "memory");   // hB landed
    __builtin_amdgcn_sched_barrier(0);
    #pragma unroll
    for (int q = 0; q < 2; ++q)
      #pragma unroll
      for (int bt = 0; bt < 4; ++bt) {
        MFA(0, bt, hB[q * 4 + bt], 4 + q);
        MFA(1, bt, hB[q * 4 + bt], 4 + q);
      }

    // partial sums -> LDS
    #pragma unroll
    for (int ct = 0; ct < 2; ++ct)
      #pragma unroll
      for (int bt = 0; bt < 4; ++bt)
        *(f32x4*)&gw[w][ct * 16 + am][bt * 16 + kg * 4] = acc[ct][bt];
    __syncthreads();   // #1: partials visible

    // reduce over 8 waves + activations; one cell per thread
    {
      float s0 = 0.f, s1 = 0.f, s2 = 0.f, s3 = 0.f;
      #pragma unroll
      for (int ww = 0; ww < 8; ++ww) {
        s0 += gw[ww][ej][eb];
        s1 += gw[ww][8 + ej][eb];
        s2 += gw[ww][16 + ej][eb];
        s3 += gw[ww][24 + ej][eb];
      }
      float pi = s0 + bias[0], pf = s1 + bias[1];
      float pg = s2 + bias[2], po = s3 + bias[3];
      c = sigmoidf_fast(pf) * c + sigmoidf_fast(pi) * tanhf_fast(pg);
      float h = sigmoidf_fast(po) * tanhf_fast(c);
      u16 hu = __builtin_bit_cast(u16, (bf16_t)h);
      u16* hp = hbuf + (size_t)(cur ^ 1) * BATCH * HDIM + (size_t)eb * HDIM + wg * JS + ej;
      asm volatile("global_store_short %0, %1, off sc0 sc1"   // write-through, peer-coherent
                   :: "v"(hp), "v"((u32)hu) : "memory");
    }
    __syncthreads();   // #2: includes vmcnt(0) -> all 8 waves' h stores at LLC

    if (t != T_STEPS - 1) {
      if (tid == 0) atomicAdd(&cnt[(wg & 7) * 32], 1u);   // arrive early

      // overlap the barrier wait with next step's X-part MFMAs
      #pragma unroll
      for (int ct = 0; ct < 2; ++ct)
        #pragma unroll
        for (int bt = 0; bt < 4; ++bt)
          acc[ct][bt] = (f32x4){0.f, 0.f, 0.f, 0.f};
      xphase(t + 1);

      if (w == 0) {   // wave 0 polls; others sleep at barrier
        u32 target = (u32)(t + 1) * (u32)NWG;
        while (true) {
          u32 v = (lane < 8)
            ? __hip_atomic_load(&cnt[lane * 32], __ATOMIC_RELAXED, __HIP_MEMORY_SCOPE_AGENT)
            : 0u;
          v += __shfl_xor(v, 1);
          v += __shfl_xor(v, 2);
          v += __shfl_xor(v, 4);
          if (__shfl(v, 0) >= target) break;
          __builtin_amdgcn_s_sleep(1);
        }
      }
      __syncthreads();   // #3: release; h(t+1) lines coherent (producer-side invalidation)
    }
    cur ^= 1;
  }
}

__global__ __launch_bounds__(TPB2) void k_out(
    const u16* __restrict__ hfin, const float* __restrict__ Who,
    const float* __restrict__ bho, float* __restrict__ out) {
  int gid = blockIdx.x * TPB2 + threadIdx.x;  // 0..32767
  int b   = gid & 63;
  int oc  = gid >> 6;
  const u16* hrow = hfin + b * HDIM;
  const float* wrow = Who + oc * HDIM;
  float s = bho[oc];
  for (int k = 0; k < HDIM; k += 8) {
    bf16x8 hv = *(const bf16x8*)(hrow + k);
    f32x4 w0 = *(const f32x4*)(wrow + k);
    f32x4 w1 = *(const f32x4*)(wrow + k + 4);
    s += (float)hv[0] * w0[0] + (float)hv[1] * w0[1] + (float)hv[2] * w0[2] + (float)hv[3] * w0[3]
       + (float)hv[4] * w1[0] + (float)hv[5] * w1[1] + (float)hv[6] * w1[2] + (float)hv[7] * w1[3];
  }
  out[b * ODIM + oc] = s;
}

extern "C" void kernel_launch(void* const* d_in, const int* in_sizes, int n_in,
                              void* d_out, int out_size, void* d_ws, size_t ws_size,
                              hipStream_t stream) {
  const float* X   = (const float*)d_in[0];
  const float* Wih = (const float*)d_in[1];
  const float* Whh = (const float*)d_in[2];
  const float* bih = (const float*)d_in[3];
  const float* bhh = (const float*)d_in[4];
  const float* Who = (const float*)d_in[5];
  const float* bho = (const float*)d_in[6];

  u32* ws32 = (u32*)d_ws;
  u16* hbuf = (u16*)d_ws;
  u32* cnt  = ws32 + HBUF_U32;
  u16* Xb   = (u16*)d_ws + XB_U16_OFF;

  k_init<<<64, TPB2, 0, stream>>>(ws32);
  k_xcvt<<<(T_STEPS * BATCH * IDIM) / (TPB2 * 8), TPB2, 0, stream>>>(X, Xb);
  k_lstm<<<NWG, TPB, 0, stream>>>(Xb, Wih, Whh, bih, bhh, hbuf, cnt);
  k_out<<<(BATCH * ODIM) / TPB2, TPB2, 0, stream>>>(hbuf, Who, bho, (float*)d_out);
}

// Round 10
// 2557.565 us; speedup vs baseline: 2.4264x; 1.4642x over previous
//
#include <hip/hip_runtime.h>
#include <hip/hip_bf16.h>

#define T_STEPS 512
#define BATCH   64
#define IDIM    512
#define HDIM    1024
#define ODIM    512
#define NWG     128           // 2 batch groups x 64 WGs
#define TPB     512           // 8 waves: K-split 8 ways
#define TPB2    256
#define JS      16            // hidden units per WG -> 64 gate cols
#define BGRP    32            // batch rows per group
#define GTGT    64            // arrivals per group barrier

typedef __bf16 bf16_t;
typedef bf16_t bf16x8 __attribute__((ext_vector_type(8)));
typedef float  f32x4  __attribute__((ext_vector_type(4)));
typedef unsigned short u16;
typedef unsigned int   u32;
typedef u16 u16x8 __attribute__((ext_vector_type(8)));

// ws layout (u32): [0,65536) h double buffer; [65536,66560) counters @128B; then X_bf16
#define HBUF_U32 65536
#define CNT_U32  1024
#define XB_U16_OFF (2 * (HBUF_U32 + CNT_U32))

__device__ __forceinline__ float sigmoidf_fast(float x) {
  return 1.0f / (1.0f + __expf(-x));
}
__device__ __forceinline__ float tanhf_fast(float x) {
  float ax = fabsf(x);
  float e  = __expf(-2.0f * ax);
  return copysignf((1.0f - e) / (1.0f + e), x);
}

__global__ void k_init(u32* w) {
  int i = blockIdx.x * blockDim.x + threadIdx.x;
  for (int idx = i; idx < HBUF_U32 + CNT_U32; idx += gridDim.x * blockDim.x) w[idx] = 0u;
}

__global__ __launch_bounds__(TPB2) void k_xcvt(const float* __restrict__ X,
                                               u16* __restrict__ Xb) {
  size_t i = ((size_t)blockIdx.x * TPB2 + threadIdx.x) * 8;
  f32x4 a = *(const f32x4*)(X + i);
  f32x4 b = *(const f32x4*)(X + i + 4);
  u16x8 o;
  o[0] = __builtin_bit_cast(u16, (bf16_t)a[0]);
  o[1] = __builtin_bit_cast(u16, (bf16_t)a[1]);
  o[2] = __builtin_bit_cast(u16, (bf16_t)a[2]);
  o[3] = __builtin_bit_cast(u16, (bf16_t)a[3]);
  o[4] = __builtin_bit_cast(u16, (bf16_t)b[0]);
  o[5] = __builtin_bit_cast(u16, (bf16_t)b[1]);
  o[6] = __builtin_bit_cast(u16, (bf16_t)b[2]);
  o[7] = __builtin_bit_cast(u16, (bf16_t)b[3]);
  *(u16x8*)(Xb + i) = o;
}

__device__ __forceinline__ bf16x8 cvt8(const float* src) {
  f32x4 u = *(const f32x4*)src;
  f32x4 v = *(const f32x4*)(src + 4);
  bf16x8 t;
  t[0] = (bf16_t)u[0]; t[1] = (bf16_t)u[1]; t[2] = (bf16_t)u[2]; t[3] = (bf16_t)u[3];
  t[4] = (bf16_t)v[0]; t[5] = (bf16_t)v[1]; t[6] = (bf16_t)v[2]; t[7] = (bf16_t)v[3];
  return t;
}

// acc[ct][bt] += A * wf[i*4+ct]   (ct = gate, i = k-tile slot of this wave)
#define MFA(CT, BT, AF, WI) \
  acc[CT][BT] = __builtin_amdgcn_mfma_f32_16x16x32_bf16((AF), wf[(WI)*4+(CT)], acc[CT][BT], 0, 0, 0)

// pinned h load, L2-cached (caching policy proven irrelevant r6 vs r8)
#define GLD(DST, PTR, OFFB) \
  asm volatile("global_load_dwordx4 %0, %1, off offset:" OFFB : "=v"(DST) : "v"(PTR))

#define GWS 36   // gw inner stride (floats): 16B-aligned, ~2-way banks both sides

__global__ __launch_bounds__(TPB, 2) void k_lstm(
    const u16* __restrict__ Xb, const float* __restrict__ Wih,
    const float* __restrict__ Whh, const float* __restrict__ bih,
    const float* __restrict__ bhh, u16* __restrict__ hbuf,
    u32* __restrict__ cnt) {
  __shared__ float gw[8][64][GWS];   // 73.7 KB cross-wave partial sums [wave][gatecol][batch32+pad]

  const int wg   = blockIdx.x;
  const int grp  = wg >> 6;          // batch group 0/1 (rows grp*32 .. +32)
  const int widx = wg & 63;          // hidden-slice index (units widx*16 .. +16)
  const int tid  = threadIdx.x;
  const int w    = tid >> 6;         // wave = k-split slice
  const int lane = tid & 63;
  const int am   = lane & 15;
  const int kg   = lane >> 4;

  // ---- time-invariant weights in registers: wave w owns k-tiles w+8i, i=0..5 ----
  // 24 frags = 96 VGPR: 4 gates (ct) x 6 k-slots
  bf16x8 wf[24];
  #pragma unroll
  for (int ct = 0; ct < 4; ++ct) {
    int gr = ct * HDIM + widx * JS + am;   // gate col ct*16+am of this WG
    #pragma unroll
    for (int i = 0; i < 2; ++i)
      wf[i * 4 + ct] = cvt8(Wih + (size_t)gr * IDIM + (w + 8 * i) * 32 + kg * 8);
    #pragma unroll
    for (int i = 2; i < 6; ++i)
      wf[i * 4 + ct] = cvt8(Whh + (size_t)gr * HDIM + (w + 8 * i) * 32 + kg * 8 - IDIM);
  }

  // epilogue: one cell per thread: local batch row ebl, unit ej
  const int ebl = tid >> 4;          // 0..31
  const int ej  = tid & 15;          // 0..15
  float bias[4];
  #pragma unroll
  for (int g = 0; g < 4; ++g) {
    int r = g * HDIM + widx * JS + ej;
    bias[g] = bih[r] + bhh[r];
  }
  float c = 0.f;

  f32x4 acc[4][2];

  // X-part phase: acc += X(tt) @ Wih-slice (L2-warm, never invalidated)
  auto xphase = [&](int tt) {
    const u16* xb = Xb + ((size_t)tt * BATCH + grp * BGRP + am) * IDIM + w * 32 + kg * 8;
    #pragma unroll
    for (int i = 0; i < 2; ++i)
      #pragma unroll
      for (int bt = 0; bt < 2; ++bt) {
        bf16x8 xa = *(const bf16x8*)(xb + (size_t)bt * 16 * IDIM + i * 256);
        MFA(0, bt, xa, i); MFA(1, bt, xa, i); MFA(2, bt, xa, i); MFA(3, bt, xa, i);
      }
  };

  // prologue: X(0) partials
  #pragma unroll
  for (int ct = 0; ct < 4; ++ct)
    #pragma unroll
    for (int bt = 0; bt < 2; ++bt)
      acc[ct][bt] = (f32x4){0.f, 0.f, 0.f, 0.f};
  xphase(0);

  int cur = 0;
  for (int t = 0; t < T_STEPS; ++t) {
    // ---- 8 pinned h loads (group rows only), counted waits ----
    // h k-tile kt = w+16+8*i2 covers h elements (kt*32 - IDIM) = w*32 + i2*256
    bf16x8 h0a, h0b, h1a, h1b, h2a, h2b, h3a, h3b;
    const u16* hb0 = hbuf + (size_t)cur * BATCH * HDIM
                   + (size_t)(grp * BGRP + am) * HDIM + w * 32 + kg * 8;
    const u16* hb1 = hb0 + 16 * HDIM;
    GLD(h0a, hb0, "0");    GLD(h0b, hb1, "0");
    GLD(h1a, hb0, "512");  GLD(h1b, hb1, "512");
    GLD(h2a, hb0, "1024"); GLD(h2b, hb1, "1024");
    GLD(h3a, hb0, "1536"); GLD(h3b, hb1, "1536");
    __builtin_amdgcn_sched_barrier(0);

    asm volatile("s_waitcnt vmcnt(4)" ::: "memory");   // h0*, h1* landed
    __builtin_amdgcn_sched_barrier(0);
    MFA(0,0,h0a,2); MFA(1,0,h0a,2); MFA(2,0,h0a,2); MFA(3,0,h0a,2);
    MFA(0,1,h0b,2); MFA(1,1,h0b,2); MFA(2,1,h0b,2); MFA(3,1,h0b,2);
    MFA(0,0,h1a,3); MFA(1,0,h1a,3); MFA(2,0,h1a,3); MFA(3,0,h1a,3);
    MFA(0,1,h1b,3); MFA(1,1,h1b,3); MFA(2,1,h1b,3); MFA(3,1,h1b,3);

    asm volatile("s_waitcnt vmcnt(0)" ::: "memory");   // h2*, h3* landed
    __builtin_amdgcn_sched_barrier(0);
    MFA(0,0,h2a,4); MFA(1,0,h2a,4); MFA(2,0,h2a,4); MFA(3,0,h2a,4);
    MFA(0,1,h2b,4); MFA(1,1,h2b,4); MFA(2,1,h2b,4); MFA(3,1,h2b,4);
    MFA(0,0,h3a,5); MFA(1,0,h3a,5); MFA(2,0,h3a,5); MFA(3,0,h3a,5);
    MFA(0,1,h3b,5); MFA(1,1,h3b,5); MFA(2,1,h3b,5); MFA(3,1,h3b,5);

    // partial sums -> LDS: [gatecol = ct*16+am][batch = bt*16+kg*4 (+i)]
    #pragma unroll
    for (int ct = 0; ct < 4; ++ct)
      #pragma unroll
      for (int bt = 0; bt < 2; ++bt)
        *(f32x4*)&gw[w][ct * 16 + am][bt * 16 + kg * 4] = acc[ct][bt];
    __syncthreads();   // #1: partials visible

    // reduce over 8 waves + activations; one cell per thread
    {
      float s0 = 0.f, s1 = 0.f, s2 = 0.f, s3 = 0.f;
      #pragma unroll
      for (int ww = 0; ww < 8; ++ww) {
        s0 += gw[ww][ej][ebl];
        s1 += gw[ww][16 + ej][ebl];
        s2 += gw[ww][32 + ej][ebl];
        s3 += gw[ww][48 + ej][ebl];
      }
      float pi = s0 + bias[0], pf = s1 + bias[1];
      float pg = s2 + bias[2], po = s3 + bias[3];
      c = sigmoidf_fast(pf) * c + sigmoidf_fast(pi) * tanhf_fast(pg);
      float h = sigmoidf_fast(po) * tanhf_fast(c);
      u16 hu = __builtin_bit_cast(u16, (bf16_t)h);
      u16* hp = hbuf + (size_t)(cur ^ 1) * BATCH * HDIM
              + (size_t)(grp * BGRP + ebl) * HDIM + widx * JS + ej;
      asm volatile("global_store_short %0, %1, off sc0 sc1"   // write-through, peer-coherent
                   :: "v"(hp), "v"((u32)hu) : "memory");
    }
    __syncthreads();   // #2: includes vmcnt(0) -> all 8 waves' h stores at LLC

    if (t != T_STEPS - 1) {
      if (tid == 0) atomicAdd(&cnt[(grp * 8 + (widx & 7)) * 32], 1u);   // group arrive

      // overlap the group-barrier wait with next step's X-part MFMAs
      #pragma unroll
      for (int ct = 0; ct < 4; ++ct)
        #pragma unroll
        for (int bt = 0; bt < 2; ++bt)
          acc[ct][bt] = (f32x4){0.f, 0.f, 0.f, 0.f};
      xphase(t + 1);

      if (w == 0) {   // wave 0 polls own group's 8 lines; others sleep at barrier
        u32 target = (u32)(t + 1) * (u32)GTGT;
        while (true) {
          u32 v = (lane < 8)
            ? __hip_atomic_load(&cnt[(grp * 8 + lane) * 32], __ATOMIC_RELAXED,
                                __HIP_MEMORY_SCOPE_AGENT)
            : 0u;
          v += __shfl_xor(v, 1);
          v += __shfl_xor(v, 2);
          v += __shfl_xor(v, 4);
          if (__shfl(v, 0) >= target) break;
          __builtin_amdgcn_s_sleep(1);
        }
      }
      __syncthreads();   // #3: release; h(t+1) lines coherent (producer-side invalidation)
    }
    cur ^= 1;
  }
}

__global__ __launch_bounds__(TPB2) void k_out(
    const u16* __restrict__ hfin, const float* __restrict__ Who,
    const float* __restrict__ bho, float* __restrict__ out) {
  int gid = blockIdx.x * TPB2 + threadIdx.x;  // 0..32767
  int b   = gid & 63;
  int oc  = gid >> 6;
  const u16* hrow = hfin + b * HDIM;
  const float* wrow = Who + oc * HDIM;
  float s = bho[oc];
  for (int k = 0; k < HDIM; k += 8) {
    bf16x8 hv = *(const bf16x8*)(hrow + k);
    f32x4 w0 = *(const f32x4*)(wrow + k);
    f32x4 w1 = *(const f32x4*)(wrow + k + 4);
    s += (float)hv[0] * w0[0] + (float)hv[1] * w0[1] + (float)hv[2] * w0[2] + (float)hv[3] * w0[3]
       + (float)hv[4] * w1[0] + (float)hv[5] * w1[1] + (float)hv[6] * w1[2] + (float)hv[7] * w1[3];
  }
  out[b * ODIM + oc] = s;
}

extern "C" void kernel_launch(void* const* d_in, const int* in_sizes, int n_in,
                              void* d_out, int out_size, void* d_ws, size_t ws_size,
                              hipStream_t stream) {
  const float* X   = (const float*)d_in[0];
  const float* Wih = (const float*)d_in[1];
  const float* Whh = (const float*)d_in[2];
  const float* bih = (const float*)d_in[3];
  const float* bhh = (const float*)d_in[4];
  const float* Who = (const float*)d_in[5];
  const float* bho = (const float*)d_in[6];

  u32* ws32 = (u32*)d_ws;
  u16* hbuf = (u16*)d_ws;
  u32* cnt  = ws32 + HBUF_U32;
  u16* Xb   = (u16*)d_ws + XB_U16_OFF;

  k_init<<<64, TPB2, 0, stream>>>(ws32);
  k_xcvt<<<(T_STEPS * BATCH * IDIM) / (TPB2 * 8), TPB2, 0, stream>>>(X, Xb);
  k_lstm<<<NWG, TPB, 0, stream>>>(Xb, Wih, Whh, bih, bhh, hbuf, cnt);
  k_out<<<(BATCH * ODIM) / TPB2, TPB2, 0, stream>>>(hbuf, Who, bho, (float*)d_out);
}

// Round 11
// 1646.648 us; speedup vs baseline: 3.7686x; 1.5532x over previous
//
#include <hip/hip_runtime.h>
#include <hip/hip_bf16.h>

#define T_STEPS 512
#define BATCH   64
#define IDIM    512
#define HDIM    1024
#define ODIM    512
#define NWG     256           // 4 batch groups x 64 hidden-slice WGs
#define TPB     512           // 8 waves: K-split 8 ways
#define TPB2    256
#define JS      16            // hidden units per WG -> 64 gate cols
#define BGRP    16            // batch rows per group
#define GTGT    64            // arrivals per group barrier

typedef __bf16 bf16_t;
typedef bf16_t bf16x8 __attribute__((ext_vector_type(8)));
typedef float  f32x4  __attribute__((ext_vector_type(4)));
typedef unsigned short u16;
typedef unsigned int   u32;
typedef u16 u16x8 __attribute__((ext_vector_type(8)));

// ws layout (u32): [0,65536) h double buffer; [65536,66560) counters @128B; then X_bf16
#define HBUF_U32 65536
#define CNT_U32  1024
#define XB_U16_OFF (2 * (HBUF_U32 + CNT_U32))

__device__ __forceinline__ float sigmoidf_fast(float x) {
  return 1.0f / (1.0f + __expf(-x));
}
__device__ __forceinline__ float tanhf_fast(float x) {
  float ax = fabsf(x);
  float e  = __expf(-2.0f * ax);
  return copysignf((1.0f - e) / (1.0f + e), x);
}

__global__ void k_init(u32* w) {
  int i = blockIdx.x * blockDim.x + threadIdx.x;
  for (int idx = i; idx < HBUF_U32 + CNT_U32; idx += gridDim.x * blockDim.x) w[idx] = 0u;
}

__global__ __launch_bounds__(TPB2) void k_xcvt(const float* __restrict__ X,
                                               u16* __restrict__ Xb) {
  size_t i = ((size_t)blockIdx.x * TPB2 + threadIdx.x) * 8;
  f32x4 a = *(const f32x4*)(X + i);
  f32x4 b = *(const f32x4*)(X + i + 4);
  u16x8 o;
  o[0] = __builtin_bit_cast(u16, (bf16_t)a[0]);
  o[1] = __builtin_bit_cast(u16, (bf16_t)a[1]);
  o[2] = __builtin_bit_cast(u16, (bf16_t)a[2]);
  o[3] = __builtin_bit_cast(u16, (bf16_t)a[3]);
  o[4] = __builtin_bit_cast(u16, (bf16_t)b[0]);
  o[5] = __builtin_bit_cast(u16, (bf16_t)b[1]);
  o[6] = __builtin_bit_cast(u16, (bf16_t)b[2]);
  o[7] = __builtin_bit_cast(u16, (bf16_t)b[3]);
  *(u16x8*)(Xb + i) = o;
}

__device__ __forceinline__ bf16x8 cvt8(const float* src) {
  f32x4 u = *(const f32x4*)src;
  f32x4 v = *(const f32x4*)(src + 4);
  bf16x8 t;
  t[0] = (bf16_t)u[0]; t[1] = (bf16_t)u[1]; t[2] = (bf16_t)u[2]; t[3] = (bf16_t)u[3];
  t[4] = (bf16_t)v[0]; t[5] = (bf16_t)v[1]; t[6] = (bf16_t)v[2]; t[7] = (bf16_t)v[3];
  return t;
}

// acc[ct] += A * wf[i*4+ct]   (ct = gate, i = k-tile slot of this wave)
#define MFA(CT, AF, WI) \
  acc[CT] = __builtin_amdgcn_mfma_f32_16x16x32_bf16((AF), wf[(WI)*4+(CT)], acc[CT], 0, 0, 0)

// pinned h load, L2-cached (caching policy proven irrelevant r6 vs r8)
#define GLD(DST, PTR, OFFB) \
  asm volatile("global_load_dwordx4 %0, %1, off offset:" OFFB : "=v"(DST) : "v"(PTR))

#define GWS 20   // gw inner stride (floats): 16B-aligned; reads ~2-way

__global__ __launch_bounds__(TPB, 2) void k_lstm(
    const u16* __restrict__ Xb, const float* __restrict__ Wih,
    const float* __restrict__ Whh, const float* __restrict__ bih,
    const float* __restrict__ bhh, u16* __restrict__ hbuf,
    u32* __restrict__ cnt) {
  __shared__ float gw[8][64][GWS];   // 40 KB cross-wave partial sums [wave][gatecol][batch16+pad]

  const int wg   = blockIdx.x;
  const int grp  = wg >> 6;          // batch group 0..3 (rows grp*16 .. +16)
  const int widx = wg & 63;          // hidden-slice index (units widx*16 .. +16)
  const int tid  = threadIdx.x;
  const int w    = tid >> 6;         // wave = k-split slice
  const int lane = tid & 63;
  const int am   = lane & 15;
  const int kg   = lane >> 4;

  // ---- time-invariant weights in registers: wave w owns k-tiles w+8i, i=0..5 ----
  // 24 frags = 96 VGPR: 4 gates (ct) x 6 k-slots
  bf16x8 wf[24];
  #pragma unroll
  for (int ct = 0; ct < 4; ++ct) {
    int gr = ct * HDIM + widx * JS + am;   // gate col ct*16+am of this WG
    #pragma unroll
    for (int i = 0; i < 2; ++i)
      wf[i * 4 + ct] = cvt8(Wih + (size_t)gr * IDIM + (w + 8 * i) * 32 + kg * 8);
    #pragma unroll
    for (int i = 2; i < 6; ++i)
      wf[i * 4 + ct] = cvt8(Whh + (size_t)gr * HDIM + (w + 8 * i) * 32 + kg * 8 - IDIM);
  }

  // epilogue: one cell per thread for tid<256: local batch row ebl, unit ej
  const int ebl = tid >> 4;          // 0..15 (for tid < 256)
  const int ej  = tid & 15;          // 0..15
  float bias[4];
  #pragma unroll
  for (int g = 0; g < 4; ++g) {
    int r = g * HDIM + widx * JS + ej;
    bias[g] = bih[r] + bhh[r];
  }
  float c = 0.f;

  f32x4 acc[4];

  // X-part phase: acc += X(tt) @ Wih-slice (L2-warm, never invalidated)
  auto xphase = [&](int tt) {
    const u16* xb = Xb + ((size_t)tt * BATCH + grp * BGRP + am) * IDIM + w * 32 + kg * 8;
    #pragma unroll
    for (int i = 0; i < 2; ++i) {
      bf16x8 xa = *(const bf16x8*)(xb + i * 256);
      MFA(0, xa, i); MFA(1, xa, i); MFA(2, xa, i); MFA(3, xa, i);
    }
  };

  // prologue: X(0) partials
  #pragma unroll
  for (int ct = 0; ct < 4; ++ct) acc[ct] = (f32x4){0.f, 0.f, 0.f, 0.f};
  xphase(0);

  int cur = 0;
  for (int t = 0; t < T_STEPS; ++t) {
    // ---- 4 pinned h loads (16 group rows), counted waits ----
    // h k-tile kt = w+16+8*i2 covers h elements w*32 + i2*256
    bf16x8 h0, h1, h2, h3;
    const u16* hb0 = hbuf + (size_t)cur * BATCH * HDIM
                   + (size_t)(grp * BGRP + am) * HDIM + w * 32 + kg * 8;
    GLD(h0, hb0, "0");
    GLD(h1, hb0, "512");
    GLD(h2, hb0, "1024");
    GLD(h3, hb0, "1536");
    __builtin_amdgcn_sched_barrier(0);

    asm volatile("s_waitcnt vmcnt(2)" ::: "memory");   // h0, h1 landed
    __builtin_amdgcn_sched_barrier(0);
    MFA(0, h0, 2); MFA(1, h0, 2); MFA(2, h0, 2); MFA(3, h0, 2);
    MFA(0, h1, 3); MFA(1, h1, 3); MFA(2, h1, 3); MFA(3, h1, 3);

    asm volatile("s_waitcnt vmcnt(0)" ::: "memory");   // h2, h3 landed
    __builtin_amdgcn_sched_barrier(0);
    MFA(0, h2, 4); MFA(1, h2, 4); MFA(2, h2, 4); MFA(3, h2, 4);
    MFA(0, h3, 5); MFA(1, h3, 5); MFA(2, h3, 5); MFA(3, h3, 5);

    // partial sums -> LDS: [gatecol = ct*16+am][batch = kg*4 (+i)]
    #pragma unroll
    for (int ct = 0; ct < 4; ++ct)
      *(f32x4*)&gw[w][ct * 16 + am][kg * 4] = acc[ct];
    __syncthreads();   // #1: partials visible

    // reduce over 8 waves + activations; one cell per thread (tid < 256)
    if (tid < 256) {
      float s0 = 0.f, s1 = 0.f, s2 = 0.f, s3 = 0.f;
      #pragma unroll
      for (int ww = 0; ww < 8; ++ww) {
        s0 += gw[ww][ej][ebl];
        s1 += gw[ww][16 + ej][ebl];
        s2 += gw[ww][32 + ej][ebl];
        s3 += gw[ww][48 + ej][ebl];
      }
      float pi = s0 + bias[0], pf = s1 + bias[1];
      float pg = s2 + bias[2], po = s3 + bias[3];
      c = sigmoidf_fast(pf) * c + sigmoidf_fast(pi) * tanhf_fast(pg);
      float h = sigmoidf_fast(po) * tanhf_fast(c);
      u16 hu = __builtin_bit_cast(u16, (bf16_t)h);
      u16* hp = hbuf + (size_t)(cur ^ 1) * BATCH * HDIM
              + (size_t)(grp * BGRP + ebl) * HDIM + widx * JS + ej;
      asm volatile("global_store_short %0, %1, off sc0 sc1"   // write-through, peer-coherent
                   :: "v"(hp), "v"((u32)hu) : "memory");
    }
    __syncthreads();   // #2: includes vmcnt(0) -> all h stores at LLC

    if (t != T_STEPS - 1) {
      if (tid == 0) atomicAdd(&cnt[(grp * 8 + (widx & 7)) * 32], 1u);   // group arrive

      // overlap the group-barrier wait with next step's X-part MFMAs
      #pragma unroll
      for (int ct = 0; ct < 4; ++ct) acc[ct] = (f32x4){0.f, 0.f, 0.f, 0.f};
      xphase(t + 1);

      if (w == 0) {   // wave 0 polls own group's 8 lines; others sleep at barrier
        u32 target = (u32)(t + 1) * (u32)GTGT;
        while (true) {
          u32 v = (lane < 8)
            ? __hip_atomic_load(&cnt[(grp * 8 + lane) * 32], __ATOMIC_RELAXED,
                                __HIP_MEMORY_SCOPE_AGENT)
            : 0u;
          v += __shfl_xor(v, 1);
          v += __shfl_xor(v, 2);
          v += __shfl_xor(v, 4);
          if (__shfl(v, 0) >= target) break;
          __builtin_amdgcn_s_sleep(1);
        }
      }
      __syncthreads();   // #3: release; h(t+1) lines coherent (producer-side invalidation)
    }
    cur ^= 1;
  }
}

__global__ __launch_bounds__(TPB2) void k_out(
    const u16* __restrict__ hfin, const float* __restrict__ Who,
    const float* __restrict__ bho, float* __restrict__ out) {
  int gid = blockIdx.x * TPB2 + threadIdx.x;  // 0..32767
  int b   = gid & 63;
  int oc  = gid >> 6;
  const u16* hrow = hfin + b * HDIM;
  const float* wrow = Who + oc * HDIM;
  float s = bho[oc];
  for (int k = 0; k < HDIM; k += 8) {
    bf16x8 hv = *(const bf16x8*)(hrow + k);
    f32x4 w0 = *(const f32x4*)(wrow + k);
    f32x4 w1 = *(const f32x4*)(wrow + k + 4);
    s += (float)hv[0] * w0[0] + (float)hv[1] * w0[1] + (float)hv[2] * w0[2] + (float)hv[3] * w0[3]
       + (float)hv[4] * w1[0] + (float)hv[5] * w1[1] + (float)hv[6] * w1[2] + (float)hv[7] * w1[3];
  }
  out[b * ODIM + oc] = s;
}

extern "C" void kernel_launch(void* const* d_in, const int* in_sizes, int n_in,
                              void* d_out, int out_size, void* d_ws, size_t ws_size,
                              hipStream_t stream) {
  const float* X   = (const float*)d_in[0];
  const float* Wih = (const float*)d_in[1];
  const float* Whh = (const float*)d_in[2];
  const float* bih = (const float*)d_in[3];
  const float* bhh = (const float*)d_in[4];
  const float* Who = (const float*)d_in[5];
  const float* bho = (const float*)d_in[6];

  u32* ws32 = (u32*)d_ws;
  u16* hbuf = (u16*)d_ws;
  u32* cnt  = ws32 + HBUF_U32;
  u16* Xb   = (u16*)d_ws + XB_U16_OFF;

  k_init<<<64, TPB2, 0, stream>>>(ws32);
  k_xcvt<<<(T_STEPS * BATCH * IDIM) / (TPB2 * 8), TPB2, 0, stream>>>(X, Xb);
  k_lstm<<<NWG, TPB, 0, stream>>>(Xb, Wih, Whh, bih, bhh, hbuf, cnt);
  k_out<<<(BATCH * ODIM) / TPB2, TPB2, 0, stream>>>(hbuf, Who, bho, (float*)d_out);
}

// Round 12
// 1454.873 us; speedup vs baseline: 4.2654x; 1.1318x over previous
//
#include <hip/hip_runtime.h>
#include <hip/hip_bf16.h>

#define T_STEPS 512
#define BATCH   64
#define IDIM    512
#define HDIM    1024
#define ODIM    512
#define NWG     256           // 4 batch groups x 64 hidden-slice WGs
#define TPB     512           // 8 waves: K-split 8 ways
#define TPB2    256
#define JS      16            // hidden units per WG -> 64 gate cols
#define BGRP    16            // batch rows per group

typedef __bf16 bf16_t;
typedef bf16_t bf16x8 __attribute__((ext_vector_type(8)));
typedef float  f32x4  __attribute__((ext_vector_type(4)));
typedef unsigned short u16;
typedef unsigned int   u32;
typedef u16 u16x8 __attribute__((ext_vector_type(8)));

// ws layout (u32): [0,65536) h double buffer; [65536,73728) 256 flags @128B; then X_bf16
#define HBUF_U32 65536
#define FLG_U32  8192
#define XB_U16_OFF (2 * (HBUF_U32 + FLG_U32))

__device__ __forceinline__ float sigmoidf_fast(float x) {
  return 1.0f / (1.0f + __expf(-x));
}
__device__ __forceinline__ float tanhf_fast(float x) {
  float ax = fabsf(x);
  float e  = __expf(-2.0f * ax);
  return copysignf((1.0f - e) / (1.0f + e), x);
}

__global__ void k_init(u32* w) {
  int i = blockIdx.x * blockDim.x + threadIdx.x;
  for (int idx = i; idx < HBUF_U32 + FLG_U32; idx += gridDim.x * blockDim.x) w[idx] = 0u;
}

__global__ __launch_bounds__(TPB2) void k_xcvt(const float* __restrict__ X,
                                               u16* __restrict__ Xb) {
  size_t i = ((size_t)blockIdx.x * TPB2 + threadIdx.x) * 8;
  f32x4 a = *(const f32x4*)(X + i);
  f32x4 b = *(const f32x4*)(X + i + 4);
  u16x8 o;
  o[0] = __builtin_bit_cast(u16, (bf16_t)a[0]);
  o[1] = __builtin_bit_cast(u16, (bf16_t)a[1]);
  o[2] = __builtin_bit_cast(u16, (bf16_t)a[2]);
  o[3] = __builtin_bit_cast(u16, (bf16_t)a[3]);
  o[4] = __builtin_bit_cast(u16, (bf16_t)b[0]);
  o[5] = __builtin_bit_cast(u16, (bf16_t)b[1]);
  o[6] = __builtin_bit_cast(u16, (bf16_t)b[2]);
  o[7] = __builtin_bit_cast(u16, (bf16_t)b[3]);
  *(u16x8*)(Xb + i) = o;
}

__device__ __forceinline__ bf16x8 cvt8(const float* src) {
  f32x4 u = *(const f32x4*)src;
  f32x4 v = *(const f32x4*)(src + 4);
  bf16x8 t;
  t[0] = (bf16_t)u[0]; t[1] = (bf16_t)u[1]; t[2] = (bf16_t)u[2]; t[3] = (bf16_t)u[3];
  t[4] = (bf16_t)v[0]; t[5] = (bf16_t)v[1]; t[6] = (bf16_t)v[2]; t[7] = (bf16_t)v[3];
  return t;
}

// acc[ct] += A * wf[i*4+ct]   (ct = gate, i = k-tile slot of this wave)
#define MFA(CT, AF, WI) \
  acc[CT] = __builtin_amdgcn_mfma_f32_16x16x32_bf16((AF), wf[(WI)*4+(CT)], acc[CT], 0, 0, 0)

// pinned h load, L2-cached (caching policy proven irrelevant r6 vs r8)
#define GLD(DST, PTR, OFFB) \
  asm volatile("global_load_dwordx4 %0, %1, off offset:" OFFB : "=v"(DST) : "v"(PTR))

#define GWS 20   // gw inner stride (floats): 16B-aligned; reads ~2-way

__global__ __launch_bounds__(TPB, 2) void k_lstm(
    const u16* __restrict__ Xb, const float* __restrict__ Wih,
    const float* __restrict__ Whh, const float* __restrict__ bih,
    const float* __restrict__ bhh, u16* __restrict__ hbuf,
    u32* __restrict__ flg) {
  __shared__ float gw[8][64][GWS];   // 40 KB cross-wave partial sums [wave][gatecol][batch16+pad]

  const int wg   = blockIdx.x;
  const int grp  = wg >> 6;          // batch group 0..3 (rows grp*16 .. +16)
  const int widx = wg & 63;          // hidden-slice index (units widx*16 .. +16)
  const int tid  = threadIdx.x;
  const int w    = tid >> 6;         // wave = k-split slice
  const int lane = tid & 63;
  const int am   = lane & 15;
  const int kg   = lane >> 4;

  // ---- time-invariant weights in registers: wave w owns k-tiles w+8i, i=0..5 ----
  bf16x8 wf[24];
  #pragma unroll
  for (int ct = 0; ct < 4; ++ct) {
    int gr = ct * HDIM + widx * JS + am;   // gate col ct*16+am of this WG
    #pragma unroll
    for (int i = 0; i < 2; ++i)
      wf[i * 4 + ct] = cvt8(Wih + (size_t)gr * IDIM + (w + 8 * i) * 32 + kg * 8);
    #pragma unroll
    for (int i = 2; i < 6; ++i)
      wf[i * 4 + ct] = cvt8(Whh + (size_t)gr * HDIM + (w + 8 * i) * 32 + kg * 8 - IDIM);
  }

  // this wave's 8 h-producers: widx_p = 2w + (j&1) + 16*(j>>1); lane j polls one
  u32* myflag = (lane < 8)
    ? flg + ((size_t)(grp * 64 + 2 * w + (lane & 1) + 16 * (lane >> 1)) * 32)
    : flg;

  // epilogue: one cell per thread for tid<256: local batch row ebl, unit ej
  const int ebl = tid >> 4;          // 0..15 (for tid < 256)
  const int ej  = tid & 15;          // 0..15
  float bias[4];
  #pragma unroll
  for (int g = 0; g < 4; ++g) {
    int r = g * HDIM + widx * JS + ej;
    bias[g] = bih[r] + bhh[r];
  }
  float c = 0.f;

  f32x4 acc[4];

  // X-part phase: acc += X(tt) @ Wih-slice (L2-warm, never invalidated)
  auto xphase = [&](int tt) {
    const u16* xb = Xb + ((size_t)tt * BATCH + grp * BGRP + am) * IDIM + w * 32 + kg * 8;
    #pragma unroll
    for (int i = 0; i < 2; ++i) {
      bf16x8 xa = *(const bf16x8*)(xb + i * 256);
      MFA(0, xa, i); MFA(1, xa, i); MFA(2, xa, i); MFA(3, xa, i);
    }
  };

  // prologue: X(0) partials (h(0)=0 from k_init; no wait needed at t=0)
  #pragma unroll
  for (int ct = 0; ct < 4; ++ct) acc[ct] = (f32x4){0.f, 0.f, 0.f, 0.f};
  xphase(0);

  int cur = 0;
  for (int t = 0; t < T_STEPS; ++t) {
    // ---- 4 pinned h loads (16 group rows), counted waits ----
    bf16x8 h0, h1, h2, h3;
    const u16* hb0 = hbuf + (size_t)cur * BATCH * HDIM
                   + (size_t)(grp * BGRP + am) * HDIM + w * 32 + kg * 8;
    GLD(h0, hb0, "0");
    GLD(h1, hb0, "512");
    GLD(h2, hb0, "1024");
    GLD(h3, hb0, "1536");
    __builtin_amdgcn_sched_barrier(0);

    asm volatile("s_waitcnt vmcnt(2)" ::: "memory");   // h0, h1 landed
    __builtin_amdgcn_sched_barrier(0);
    MFA(0, h0, 2); MFA(1, h0, 2); MFA(2, h0, 2); MFA(3, h0, 2);
    MFA(0, h1, 3); MFA(1, h1, 3); MFA(2, h1, 3); MFA(3, h1, 3);

    asm volatile("s_waitcnt vmcnt(0)" ::: "memory");   // h2, h3 landed
    __builtin_amdgcn_sched_barrier(0);
    MFA(0, h2, 4); MFA(1, h2, 4); MFA(2, h2, 4); MFA(3, h2, 4);
    MFA(0, h3, 5); MFA(1, h3, 5); MFA(2, h3, 5); MFA(3, h3, 5);

    // partial sums -> LDS: [gatecol = ct*16+am][batch = kg*4 (+i)]
    #pragma unroll
    for (int ct = 0; ct < 4; ++ct)
      *(f32x4*)&gw[w][ct * 16 + am][kg * 4] = acc[ct];
    __syncthreads();   // #1: partials visible

    // reduce over 8 waves + activations; one cell per thread (tid < 256)
    if (tid < 256) {
      float s0 = 0.f, s1 = 0.f, s2 = 0.f, s3 = 0.f;
      #pragma unroll
      for (int ww = 0; ww < 8; ++ww) {
        s0 += gw[ww][ej][ebl];
        s1 += gw[ww][16 + ej][ebl];
        s2 += gw[ww][32 + ej][ebl];
        s3 += gw[ww][48 + ej][ebl];
      }
      float pi = s0 + bias[0], pf = s1 + bias[1];
      float pg = s2 + bias[2], po = s3 + bias[3];
      c = sigmoidf_fast(pf) * c + sigmoidf_fast(pi) * tanhf_fast(pg);
      float h = sigmoidf_fast(po) * tanhf_fast(c);
      u16 hu = __builtin_bit_cast(u16, (bf16_t)h);
      u16* hp = hbuf + (size_t)(cur ^ 1) * BATCH * HDIM
              + (size_t)(grp * BGRP + ebl) * HDIM + widx * JS + ej;
      asm volatile("global_store_short %0, %1, off sc0 sc1"   // write-through, peer-coherent
                   :: "v"(hp), "v"((u32)hu) : "memory");
    }
    __syncthreads();   // #2: each wave drains vmcnt before barrier -> all h stores at LLC

    if (t != T_STEPS - 1) {
      // publish: this WG's h(t+1) slice is complete (one writer per flag)
      if (tid == 0) {
        u32 fv = (u32)(t + 1);
        u32* fp = flg + (size_t)(grp * 64 + widx) * 32;
        asm volatile("global_store_dword %0, %1, off sc0 sc1"
                     :: "v"(fp), "v"(fv) : "memory");
      }

      // overlap wait with next step's X-part MFMAs
      #pragma unroll
      for (int ct = 0; ct < 4; ++ct) acc[ct] = (f32x4){0.f, 0.f, 0.f, 0.f};
      xphase(t + 1);

      // per-wave dataflow wait: only this wave's 8 producers (lanes 0-7 poll)
      {
        const u32 tgt = (u32)(t + 1);
        while (true) {
          u32 v = (lane < 8)
            ? __hip_atomic_load(myflag, __ATOMIC_RELAXED, __HIP_MEMORY_SCOPE_AGENT)
            : tgt;
          if (__all((int)(v >= tgt))) break;
          __builtin_amdgcn_s_sleep(1);
        }
      }
      __builtin_amdgcn_sched_barrier(0);
    }
    cur ^= 1;
  }
}

__global__ __launch_bounds__(TPB2) void k_out(
    const u16* __restrict__ hfin, const float* __restrict__ Who,
    const float* __restrict__ bho, float* __restrict__ out) {
  int gid = blockIdx.x * TPB2 + threadIdx.x;  // 0..32767
  int b   = gid & 63;
  int oc  = gid >> 6;
  const u16* hrow = hfin + b * HDIM;
  const float* wrow = Who + oc * HDIM;
  float s = bho[oc];
  for (int k = 0; k < HDIM; k += 8) {
    bf16x8 hv = *(const bf16x8*)(hrow + k);
    f32x4 w0 = *(const f32x4*)(wrow + k);
    f32x4 w1 = *(const f32x4*)(wrow + k + 4);
    s += (float)hv[0] * w0[0] + (float)hv[1] * w0[1] + (float)hv[2] * w0[2] + (float)hv[3] * w0[3]
       + (float)hv[4] * w1[0] + (float)hv[5] * w1[1] + (float)hv[6] * w1[2] + (float)hv[7] * w1[3];
  }
  out[b * ODIM + oc] = s;
}

extern "C" void kernel_launch(void* const* d_in, const int* in_sizes, int n_in,
                              void* d_out, int out_size, void* d_ws, size_t ws_size,
                              hipStream_t stream) {
  const float* X   = (const float*)d_in[0];
  const float* Wih = (const float*)d_in[1];
  const float* Whh = (const float*)d_in[2];
  const float* bih = (const float*)d_in[3];
  const float* bhh = (const float*)d_in[4];
  const float* Who = (const float*)d_in[5];
  const float* bho = (const float*)d_in[6];

  u32* ws32 = (u32*)d_ws;
  u16* hbuf = (u16*)d_ws;
  u32* flg  = ws32 + HBUF_U32;
  u16* Xb   = (u16*)d_ws + XB_U16_OFF;

  k_init<<<64, TPB2, 0, stream>>>(ws32);
  k_xcvt<<<(T_STEPS * BATCH * IDIM) / (TPB2 * 8), TPB2, 0, stream>>>(X, Xb);
  k_lstm<<<NWG, TPB, 0, stream>>>(Xb, Wih, Whh, bih, bhh, hbuf, flg);
  k_out<<<(BATCH * ODIM) / TPB2, TPB2, 0, stream>>>(hbuf, Who, bho, (float*)d_out);
}

// Round 13
// 1452.414 us; speedup vs baseline: 4.2726x; 1.0017x over previous
//
#include <hip/hip_runtime.h>
#include <hip/hip_bf16.h>

#define T_STEPS 512
#define BATCH   64
#define IDIM    512
#define HDIM    1024
#define ODIM    512
#define NWG     256           // 4 batch groups x 64 hidden-slice WGs
#define TPB     512           // 8 waves: K-split 8 ways
#define TPB2    256
#define JS      16            // hidden units per WG -> 64 gate cols
#define BGRP    16            // batch rows per group

typedef __bf16 bf16_t;
typedef bf16_t bf16x8 __attribute__((ext_vector_type(8)));
typedef float  f32x4  __attribute__((ext_vector_type(4)));
typedef unsigned short u16;
typedef unsigned int   u32;
typedef u16 u16x8 __attribute__((ext_vector_type(8)));

// ws layout (u32): [0,65536) h double buffer; [65536,73728) 256 flags @128B; then X_bf16
#define HBUF_U32 65536
#define FLG_U32  8192
#define XB_U16_OFF (2 * (HBUF_U32 + FLG_U32))

__device__ __forceinline__ float sigmoidf_fast(float x) {
  return 1.0f / (1.0f + __expf(-x));
}
__device__ __forceinline__ float tanhf_fast(float x) {
  float ax = fabsf(x);
  float e  = __expf(-2.0f * ax);
  return copysignf((1.0f - e) / (1.0f + e), x);
}

__global__ void k_init(u32* w) {
  int i = blockIdx.x * blockDim.x + threadIdx.x;
  for (int idx = i; idx < HBUF_U32 + FLG_U32; idx += gridDim.x * blockDim.x) w[idx] = 0u;
}

__global__ __launch_bounds__(TPB2) void k_xcvt(const float* __restrict__ X,
                                               u16* __restrict__ Xb) {
  size_t i = ((size_t)blockIdx.x * TPB2 + threadIdx.x) * 8;
  f32x4 a = *(const f32x4*)(X + i);
  f32x4 b = *(const f32x4*)(X + i + 4);
  u16x8 o;
  o[0] = __builtin_bit_cast(u16, (bf16_t)a[0]);
  o[1] = __builtin_bit_cast(u16, (bf16_t)a[1]);
  o[2] = __builtin_bit_cast(u16, (bf16_t)a[2]);
  o[3] = __builtin_bit_cast(u16, (bf16_t)a[3]);
  o[4] = __builtin_bit_cast(u16, (bf16_t)b[0]);
  o[5] = __builtin_bit_cast(u16, (bf16_t)b[1]);
  o[6] = __builtin_bit_cast(u16, (bf16_t)b[2]);
  o[7] = __builtin_bit_cast(u16, (bf16_t)b[3]);
  *(u16x8*)(Xb + i) = o;
}

__device__ __forceinline__ bf16x8 cvt8(const float* src) {
  f32x4 u = *(const f32x4*)src;
  f32x4 v = *(const f32x4*)(src + 4);
  bf16x8 t;
  t[0] = (bf16_t)u[0]; t[1] = (bf16_t)u[1]; t[2] = (bf16_t)u[2]; t[3] = (bf16_t)u[3];
  t[4] = (bf16_t)v[0]; t[5] = (bf16_t)v[1]; t[6] = (bf16_t)v[2]; t[7] = (bf16_t)v[3];
  return t;
}

// acc[ct] += A * wf[i*4+ct]   (ct = gate, i = k-tile slot of this wave)
#define MFA(CT, AF, WI) \
  acc[CT] = __builtin_amdgcn_mfma_f32_16x16x32_bf16((AF), wf[(WI)*4+(CT)], acc[CT], 0, 0, 0)

// pinned h load, LLC-coherent (sc0 sc1): reads at the coherence point, immune to
// in-flight peer-L2 invalidations (r12's absmax wobble). Perf-neutral: r6 === r8.
#define GLDH(DST, PTR, OFFB) \
  asm volatile("global_load_dwordx4 %0, %1, off offset:" OFFB " sc0 sc1" : "=v"(DST) : "v"(PTR))

#define GWS 20   // gw inner stride (floats): 16B-aligned; reads ~2-way

__global__ __launch_bounds__(TPB, 2) void k_lstm(
    const u16* __restrict__ Xb, const float* __restrict__ Wih,
    const float* __restrict__ Whh, const float* __restrict__ bih,
    const float* __restrict__ bhh, u16* __restrict__ hbuf,
    u32* __restrict__ flg) {
  __shared__ float gw[8][64][GWS];   // 40 KB cross-wave partial sums [wave][gatecol][batch16+pad]

  const int wg   = blockIdx.x;
  const int grp  = wg >> 6;          // batch group 0..3 (rows grp*16 .. +16)
  const int widx = wg & 63;          // hidden-slice index (units widx*16 .. +16)
  const int tid  = threadIdx.x;
  const int w    = tid >> 6;         // wave = k-split slice
  const int lane = tid & 63;
  const int am   = lane & 15;
  const int kg   = lane >> 4;

  // ---- time-invariant weights in registers: wave w owns k-tiles w+8i, i=0..5 ----
  bf16x8 wf[24];
  #pragma unroll
  for (int ct = 0; ct < 4; ++ct) {
    int gr = ct * HDIM + widx * JS + am;   // gate col ct*16+am of this WG
    #pragma unroll
    for (int i = 0; i < 2; ++i)
      wf[i * 4 + ct] = cvt8(Wih + (size_t)gr * IDIM + (w + 8 * i) * 32 + kg * 8);
    #pragma unroll
    for (int i = 2; i < 6; ++i)
      wf[i * 4 + ct] = cvt8(Whh + (size_t)gr * HDIM + (w + 8 * i) * 32 + kg * 8 - IDIM);
  }

  // this wave's 8 h-producers: widx_p = 2w + (j&1) + 16*(j>>1); lane j polls one
  u32* myflag = (lane < 8)
    ? flg + ((size_t)(grp * 64 + 2 * w + (lane & 1) + 16 * (lane >> 1)) * 32)
    : flg;

  // epilogue: one cell per thread for tid<256: local batch row ebl, unit ej
  const int ebl = tid >> 4;          // 0..15 (for tid < 256)
  const int ej  = tid & 15;          // 0..15
  float bias[4];
  #pragma unroll
  for (int g = 0; g < 4; ++g) {
    int r = g * HDIM + widx * JS + ej;
    bias[g] = bih[r] + bhh[r];
  }
  float c = 0.f;

  f32x4 acc[4];

  // X-part phase: acc += X(tt) @ Wih-slice (L2-warm, never invalidated)
  auto xphase = [&](int tt) {
    const u16* xb = Xb + ((size_t)tt * BATCH + grp * BGRP + am) * IDIM + w * 32 + kg * 8;
    #pragma unroll
    for (int i = 0; i < 2; ++i) {
      bf16x8 xa = *(const bf16x8*)(xb + i * 256);
      MFA(0, xa, i); MFA(1, xa, i); MFA(2, xa, i); MFA(3, xa, i);
    }
  };

  // prologue: X(0) partials (h(0)=0 from k_init; no wait needed at t=0)
  #pragma unroll
  for (int ct = 0; ct < 4; ++ct) acc[ct] = (f32x4){0.f, 0.f, 0.f, 0.f};
  xphase(0);

  int cur = 0;
  for (int t = 0; t < T_STEPS; ++t) {
    // ---- 4 pinned h loads (LLC-coherent), counted waits ----
    bf16x8 h0, h1, h2, h3;
    const u16* hb0 = hbuf + (size_t)cur * BATCH * HDIM
                   + (size_t)(grp * BGRP + am) * HDIM + w * 32 + kg * 8;
    GLDH(h0, hb0, "0");
    GLDH(h1, hb0, "512");
    GLDH(h2, hb0, "1024");
    GLDH(h3, hb0, "1536");
    __builtin_amdgcn_sched_barrier(0);

    asm volatile("s_waitcnt vmcnt(2)" ::: "memory");   // h0, h1 landed
    __builtin_amdgcn_sched_barrier(0);
    MFA(0, h0, 2); MFA(1, h0, 2); MFA(2, h0, 2); MFA(3, h0, 2);
    MFA(0, h1, 3); MFA(1, h1, 3); MFA(2, h1, 3); MFA(3, h1, 3);

    asm volatile("s_waitcnt vmcnt(0)" ::: "memory");   // h2, h3 landed
    __builtin_amdgcn_sched_barrier(0);
    MFA(0, h2, 4); MFA(1, h2, 4); MFA(2, h2, 4); MFA(3, h2, 4);
    MFA(0, h3, 5); MFA(1, h3, 5); MFA(2, h3, 5); MFA(3, h3, 5);

    // partial sums -> LDS: [gatecol = ct*16+am][batch = kg*4 (+i)]
    #pragma unroll
    for (int ct = 0; ct < 4; ++ct)
      *(f32x4*)&gw[w][ct * 16 + am][kg * 4] = acc[ct];
    __syncthreads();   // #1: partials visible

    // reduce over 8 waves + activations; one cell per thread (tid < 256)
    if (tid < 256) {
      float s0 = 0.f, s1 = 0.f, s2 = 0.f, s3 = 0.f;
      #pragma unroll
      for (int ww = 0; ww < 8; ++ww) {
        s0 += gw[ww][ej][ebl];
        s1 += gw[ww][16 + ej][ebl];
        s2 += gw[ww][32 + ej][ebl];
        s3 += gw[ww][48 + ej][ebl];
      }
      float pi = s0 + bias[0], pf = s1 + bias[1];
      float pg = s2 + bias[2], po = s3 + bias[3];
      c = sigmoidf_fast(pf) * c + sigmoidf_fast(pi) * tanhf_fast(pg);
      float h = sigmoidf_fast(po) * tanhf_fast(c);
      u16 hu = __builtin_bit_cast(u16, (bf16_t)h);
      u16* hp = hbuf + (size_t)(cur ^ 1) * BATCH * HDIM
              + (size_t)(grp * BGRP + ebl) * HDIM + widx * JS + ej;
      asm volatile("global_store_short %0, %1, off sc0 sc1"   // write-through to LLC
                   :: "v"(hp), "v"((u32)hu) : "memory");
    }
    __syncthreads();   // #2: each wave drains vmcnt before barrier -> all h stores at LLC

    if (t != T_STEPS - 1) {
      // publish: this WG's h(t+1) slice is complete (one writer per flag)
      if (tid == 0) {
        u32 fv = (u32)(t + 1);
        u32* fp = flg + (size_t)(grp * 64 + widx) * 32;
        asm volatile("global_store_dword %0, %1, off sc0 sc1"
                     :: "v"(fp), "v"(fv) : "memory");
      }

      // overlap wait with next step's X-part MFMAs
      #pragma unroll
      for (int ct = 0; ct < 4; ++ct) acc[ct] = (f32x4){0.f, 0.f, 0.f, 0.f};
      xphase(t + 1);

      // per-wave dataflow wait: only this wave's 8 producers (lanes 0-7 poll)
      {
        const u32 tgt = (u32)(t + 1);
        while (true) {
          u32 v = (lane < 8)
            ? __hip_atomic_load(myflag, __ATOMIC_RELAXED, __HIP_MEMORY_SCOPE_AGENT)
            : tgt;
          if (__all((int)(v >= tgt))) break;
          __builtin_amdgcn_s_sleep(1);
        }
      }
      __builtin_amdgcn_sched_barrier(0);
    }
    cur ^= 1;
  }
}

__global__ __launch_bounds__(TPB2) void k_out(
    const u16* __restrict__ hfin, const float* __restrict__ Who,
    const float* __restrict__ bho, float* __restrict__ out) {
  int gid = blockIdx.x * TPB2 + threadIdx.x;  // 0..32767
  int b   = gid & 63;
  int oc  = gid >> 6;
  const u16* hrow = hfin + b * HDIM;
  const float* wrow = Who + oc * HDIM;
  float s = bho[oc];
  for (int k = 0; k < HDIM; k += 8) {
    bf16x8 hv = *(const bf16x8*)(hrow + k);
    f32x4 w0 = *(const f32x4*)(wrow + k);
    f32x4 w1 = *(const f32x4*)(wrow + k + 4);
    s += (float)hv[0] * w0[0] + (float)hv[1] * w0[1] + (float)hv[2] * w0[2] + (float)hv[3] * w0[3]
       + (float)hv[4] * w1[0] + (float)hv[5] * w1[1] + (float)hv[6] * w1[2] + (float)hv[7] * w1[3];
  }
  out[b * ODIM + oc] = s;
}

extern "C" void kernel_launch(void* const* d_in, const int* in_sizes, int n_in,
                              void* d_out, int out_size, void* d_ws, size_t ws_size,
                              hipStream_t stream) {
  const float* X   = (const float*)d_in[0];
  const float* Wih = (const float*)d_in[1];
  const float* Whh = (const float*)d_in[2];
  const float* bih = (const float*)d_in[3];
  const float* bhh = (const float*)d_in[4];
  const float* Who = (const float*)d_in[5];
  const float* bho = (const float*)d_in[6];

  u32* ws32 = (u32*)d_ws;
  u16* hbuf = (u16*)d_ws;
  u32* flg  = ws32 + HBUF_U32;
  u16* Xb   = (u16*)d_ws + XB_U16_OFF;

  k_init<<<64, TPB2, 0, stream>>>(ws32);
  k_xcvt<<<(T_STEPS * BATCH * IDIM) / (TPB2 * 8), TPB2, 0, stream>>>(X, Xb);
  k_lstm<<<NWG, TPB, 0, stream>>>(Xb, Wih, Whh, bih, bhh, hbuf, flg);
  k_out<<<(BATCH * ODIM) / TPB2, TPB2, 0, stream>>>(hbuf, Who, bho, (float*)d_out);
}